// Round 2
// baseline (24842.253 us; speedup 1.0000x reference)
//
#include <hip/hip_runtime.h>
#include <math.h>

// 2-layer LSTM, B=64, T=512, F=256, H=512, fp32 — persistent cooperative kernel.
// One launch; T-loop inside; grid barrier per macro-step (ping-pong h buffers
// make a single barrier sufficient: step s writes buf[s&1], reads buf[(s+1)&1]).
// Partition identical to the verified R1 kernel:
//   blocks [0,128):  layer0, tile = blockIdx.x     (4 hidden units, 16 gate rows)
//   blocks [128,256): layer1, tile = blockIdx.x-128
//   8 waves/block split K; lane = batch b; weights read at wave-uniform
//   addresses -> s_load, resident in L2/sL1 across all 512 steps.
// h state transposed+4-blocked in ws: hT[k/4][b][4] for coalesced float4 loads.

#define TT 512
#define FF 256
#define HH 512
#define NB 256

__device__ __forceinline__ float sigmoidf_(float v) {
    return 1.0f / (1.0f + __expf(-v));
}

__global__ void __launch_bounds__(512, 2) lstm_persist(
    const float* __restrict__ x,
    const float* __restrict__ Wih0, const float* __restrict__ Whh0,
    const float* __restrict__ bi0,  const float* __restrict__ bh0,
    const float* __restrict__ Wih1, const float* __restrict__ Whh1,
    const float* __restrict__ bi1,  const float* __restrict__ bh1,
    float* __restrict__ h0T, float* __restrict__ c0,
    float* __restrict__ h1T, float* __restrict__ c1,
    float* __restrict__ out, int* __restrict__ bar)
{
    const int layer = blockIdx.x >> 7;
    const int tile  = blockIdx.x & 127;
    const int ub    = tile << 2;          // 4 hidden units per block
    const int tid   = threadIdx.x;
    const int lane  = tid & 63;           // = batch index b
    const int wv    = __builtin_amdgcn_readfirstlane(tid >> 6);  // wave id, uniform

    __shared__ float gsh[16][64];         // [g*4+ul][b] gate pre-activations

    const float* bi = layer ? bi1 : bi0;
    const float* bh = layer ? bh1 : bh0;
    int* cnt   = bar;                     // arrival counter
    int* phase = bar + 32;                // separate cacheline

    for (int s = 0; s <= TT; ++s) {
        const bool active = layer ? (s > 0) : (s < TT);
        if (active) {
            const int t = layer ? (s - 1) : s;

            // init gates with biases
            for (int q = tid; q < 16 * 64; q += 512) {
                const int jj = q >> 6, b = q & 63;
                const int jg = ((jj >> 2) << 9) + ub + (jj & 3);   // g*512 + u
                gsh[jj][b] = bi[jg] + bh[jg];
            }

            float acc[16];
#pragma unroll
            for (int j = 0; j < 16; ++j) acc[j] = 0.0f;

            if (layer == 0) {
                // segment 1: x_t @ Wih0^T, K=256; wave slice [wv*32, +32)
                const float* xrow = x + ((size_t)lane * TT + t) * FF;
                const int kx0 = wv * 32;
                for (int kc = 0; kc < 32; kc += 4) {
                    const int k = kx0 + kc;
                    const float4 hv = *(const float4*)(xrow + k);
#pragma unroll
                    for (int j = 0; j < 16; ++j) {
                        const int jg = ((j >> 2) << 9) + ub + (j & 3);
                        const float* wr = Wih0 + (size_t)jg * FF + k;   // uniform -> s_load
                        acc[j] = fmaf(hv.x, wr[0], acc[j]);
                        acc[j] = fmaf(hv.y, wr[1], acc[j]);
                        acc[j] = fmaf(hv.z, wr[2], acc[j]);
                        acc[j] = fmaf(hv.w, wr[3], acc[j]);
                    }
                }
                // segment 2: h0[t-1] @ Whh0^T, K=512; wave slice [wv*64, +64)
                const float* hsrc = h0T + (((t + 1) & 1) << 15);
                const int kh0 = wv * 64;
                for (int kc = 0; kc < 64; kc += 4) {
                    const int k = kh0 + kc;
                    const float4 hv = *(const float4*)(hsrc + ((k >> 2) << 8) + (lane << 2));
#pragma unroll
                    for (int j = 0; j < 16; ++j) {
                        const int jg = ((j >> 2) << 9) + ub + (j & 3);
                        const float* wr = Whh0 + (size_t)jg * HH + k;
                        acc[j] = fmaf(hv.x, wr[0], acc[j]);
                        acc[j] = fmaf(hv.y, wr[1], acc[j]);
                        acc[j] = fmaf(hv.z, wr[2], acc[j]);
                        acc[j] = fmaf(hv.w, wr[3], acc[j]);
                    }
                }
            } else {
                // layer1 @ t=s-1: input = h0[t], hidden = h1[t-1]
                const float* hin   = h0T + (((s - 1) & 1) << 15);
                const float* hprev = h1T + ((s & 1) << 15);
                const int kh0 = wv * 64;
                for (int kc = 0; kc < 64; kc += 4) {
                    const int k = kh0 + kc;
                    const float4 hv = *(const float4*)(hin + ((k >> 2) << 8) + (lane << 2));
#pragma unroll
                    for (int j = 0; j < 16; ++j) {
                        const int jg = ((j >> 2) << 9) + ub + (j & 3);
                        const float* wr = Wih1 + (size_t)jg * HH + k;
                        acc[j] = fmaf(hv.x, wr[0], acc[j]);
                        acc[j] = fmaf(hv.y, wr[1], acc[j]);
                        acc[j] = fmaf(hv.z, wr[2], acc[j]);
                        acc[j] = fmaf(hv.w, wr[3], acc[j]);
                    }
                }
                for (int kc = 0; kc < 64; kc += 4) {
                    const int k = kh0 + kc;
                    const float4 hv = *(const float4*)(hprev + ((k >> 2) << 8) + (lane << 2));
#pragma unroll
                    for (int j = 0; j < 16; ++j) {
                        const int jg = ((j >> 2) << 9) + ub + (j & 3);
                        const float* wr = Whh1 + (size_t)jg * HH + k;
                        acc[j] = fmaf(hv.x, wr[0], acc[j]);
                        acc[j] = fmaf(hv.y, wr[1], acc[j]);
                        acc[j] = fmaf(hv.z, wr[2], acc[j]);
                        acc[j] = fmaf(hv.w, wr[3], acc[j]);
                    }
                }
            }

            __syncthreads();
#pragma unroll
            for (int j = 0; j < 16; ++j) atomicAdd(&gsh[j][lane], acc[j]);
            __syncthreads();

            if (tid < 256) {               // 4 u x 64 b state updates
                const int b  = tid & 63;
                const int ul = tid >> 6;
                const int u  = ub + ul;
                const float iv = sigmoidf_(gsh[ul][b]);
                const float fv = sigmoidf_(gsh[4 + ul][b]);
                const float gv = tanhf(gsh[8 + ul][b]);
                const float ov = sigmoidf_(gsh[12 + ul][b]);
                float* cbuf = layer ? c1 : c0;
                const size_t ci = ((size_t)b << 9) + u;
                const float cn = fv * cbuf[ci] + iv * gv;
                cbuf[ci] = cn;
                const float hn = ov * tanhf(cn);
                float* hTn = layer ? (h1T + (((s - 1) & 1) << 15))
                                   : (h0T + ((s & 1) << 15));
                hTn[((size_t)tile << 8) + (b << 2) + ul] = hn;   // hT[u/4][b][u%4]
                if (layer) out[(((size_t)b * TT) + t) * HH + u] = hn;
            }
        }

        // ---- grid barrier (sense-reversing, device scope) ----
        __syncthreads();                  // all block threads done; stores drained (vmcnt0)
        if (tid == 0) {
            __threadfence();              // release: write back so other XCDs see h/c/out
            const int ph = __hip_atomic_load(phase, __ATOMIC_RELAXED, __HIP_MEMORY_SCOPE_AGENT);
            const int tk = __hip_atomic_fetch_add(cnt, 1, __ATOMIC_ACQ_REL, __HIP_MEMORY_SCOPE_AGENT);
            if (tk == NB - 1) {
                __hip_atomic_store(cnt, 0, __ATOMIC_RELAXED, __HIP_MEMORY_SCOPE_AGENT);
                __hip_atomic_fetch_add(phase, 1, __ATOMIC_RELEASE, __HIP_MEMORY_SCOPE_AGENT);
            } else {
                while (__hip_atomic_load(phase, __ATOMIC_RELAXED, __HIP_MEMORY_SCOPE_AGENT) == ph)
                    __builtin_amdgcn_s_sleep(2);
            }
            __threadfence();              // acquire: invalidate stale cached h/c
        }
        __syncthreads();
    }
}

extern "C" void kernel_launch(void* const* d_in, const int* in_sizes, int n_in,
                              void* d_out, int out_size, void* d_ws, size_t ws_size,
                              hipStream_t stream) {
    (void)in_sizes; (void)n_in; (void)out_size; (void)ws_size;
    const float* x    = (const float*)d_in[0];
    const float* Wih0 = (const float*)d_in[1];
    const float* Whh0 = (const float*)d_in[2];
    const float* bi0  = (const float*)d_in[3];
    const float* bh0  = (const float*)d_in[4];
    const float* Wih1 = (const float*)d_in[5];
    const float* Whh1 = (const float*)d_in[6];
    const float* bi1  = (const float*)d_in[7];
    const float* bh1  = (const float*)d_in[8];
    float* out = (float*)d_out;
    float* ws  = (float*)d_ws;

    // ws layout (floats): h0T pp [2][32768] | c0 [32768] | h1T pp [2][32768] | c1 [32768] | barrier
    float* h0T = ws;
    float* c0  = ws + 65536;
    float* h1T = ws + 98304;
    float* c1  = ws + 163840;
    int*   bar = (int*)(ws + 196608);

    // zero state + barrier vars (ws is re-poisoned 0xAA before every timed call)
    hipMemsetAsync(d_ws, 0, 196608 * sizeof(float) + 256, stream);

    void* args[] = {
        (void*)&x, (void*)&Wih0, (void*)&Whh0, (void*)&bi0, (void*)&bh0,
        (void*)&Wih1, (void*)&Whh1, (void*)&bi1, (void*)&bh1,
        (void*)&h0T, (void*)&c0, (void*)&h1T, (void*)&c1,
        (void*)&out, (void*)&bar
    };
    hipLaunchCooperativeKernel((const void*)lstm_persist, dim3(NB), dim3(512),
                               args, 0, stream);
}

// Round 3
// 18693.811 us; speedup vs baseline: 1.3289x; 1.3289x over previous
//
#include <hip/hip_runtime.h>
#include <math.h>

// 2-layer LSTM, B=64, T=512, F=256, H=512, fp32 — persistent cooperative kernel.
// R3: no __threadfence (R2's per-step agent fence invalidated the whole L2 and
// forced weight refetch every step -> VALUBusy 7%). Only h0T/h1T cross block
// boundaries; they are exchanged via relaxed AGENT-scope atomics (coherent at
// L3, no cache flush). c is block-private, out write-only, weights/x read-only
// -> all stay in normal cached memory, weights hot in L2 across all 512 steps.
// Grid barrier: relaxed flag atomics; ordering via __syncthreads' vmcnt(0)
// drain (h stores acked at coherence point before the arrive token is sent).
//
// Partition (as verified R1/R2):
//   blocks [0,128):  layer0, tile = blockIdx.x     (4 hidden units, 16 gate rows)
//   blocks [128,256): layer1, tile = blockIdx.x-128
//   8 waves/block split K; lane = batch b; weights read at wave-uniform
//   addresses -> s_load. h state transposed+4-blocked: hT[k/4][b][4].

#define TT 512
#define FF 256
#define HH 512
#define NB 256

__device__ __forceinline__ float sigmoidf_(float v) {
    return 1.0f / (1.0f + __expf(-v));
}

__device__ __forceinline__ float ldg_coh(const float* p) {
    return __hip_atomic_load(p, __ATOMIC_RELAXED, __HIP_MEMORY_SCOPE_AGENT);
}
__device__ __forceinline__ void stg_coh(float* p, float v) {
    __hip_atomic_store(p, v, __ATOMIC_RELAXED, __HIP_MEMORY_SCOPE_AGENT);
}

__global__ void __launch_bounds__(512, 2) lstm_persist(
    const float* __restrict__ x,
    const float* __restrict__ Wih0, const float* __restrict__ Whh0,
    const float* __restrict__ bi0,  const float* __restrict__ bh0,
    const float* __restrict__ Wih1, const float* __restrict__ Whh1,
    const float* __restrict__ bi1,  const float* __restrict__ bh1,
    float* __restrict__ h0T, float* __restrict__ c0,
    float* __restrict__ h1T, float* __restrict__ c1,
    float* __restrict__ out, int* __restrict__ bar)
{
    const int layer = blockIdx.x >> 7;
    const int tile  = blockIdx.x & 127;
    const int ub    = tile << 2;          // 4 hidden units per block
    const int tid   = threadIdx.x;
    const int lane  = tid & 63;           // = batch index b
    const int wv    = __builtin_amdgcn_readfirstlane(tid >> 6);  // wave id, uniform

    __shared__ float gsh[16][64];         // [g*4+ul][b] gate pre-activations

    const float* bi = layer ? bi1 : bi0;
    const float* bh = layer ? bh1 : bh0;
    int* cnt   = bar;                     // arrival counter
    int* phase = bar + 32;                // separate cacheline

    for (int s = 0; s <= TT; ++s) {
        const bool active = layer ? (s > 0) : (s < TT);
        if (active) {
            const int t = layer ? (s - 1) : s;

            // init gates with biases
            for (int q = tid; q < 16 * 64; q += 512) {
                const int jj = q >> 6, b = q & 63;
                const int jg = ((jj >> 2) << 9) + ub + (jj & 3);   // g*512 + u
                gsh[jj][b] = bi[jg] + bh[jg];
            }

            float acc[16];
#pragma unroll
            for (int j = 0; j < 16; ++j) acc[j] = 0.0f;

            const int kh0 = wv * 64;
            float hl[64];

            if (layer == 0) {
                // ---- segment 1: x_t @ Wih0^T, K=256; wave slice [wv*32, +32)
                const float* xrow = x + ((size_t)lane * TT + t) * FF;
                const int kx0 = wv * 32;
                for (int kc = 0; kc < 32; kc += 4) {
                    const int k = kx0 + kc;
                    const float4 hv = *(const float4*)(xrow + k);
#pragma unroll
                    for (int j = 0; j < 16; ++j) {
                        const int jg = ((j >> 2) << 9) + ub + (j & 3);
                        const float* wr = Wih0 + (size_t)jg * FF + k;   // uniform -> s_load
                        acc[j] = fmaf(hv.x, wr[0], acc[j]);
                        acc[j] = fmaf(hv.y, wr[1], acc[j]);
                        acc[j] = fmaf(hv.z, wr[2], acc[j]);
                        acc[j] = fmaf(hv.w, wr[3], acc[j]);
                    }
                }
                // ---- segment 2: h0[t-1] @ Whh0^T; coherent loads, hoisted
                const float* hb = h0T + (((t + 1) & 1) << 15)
                                + ((kh0 >> 2) << 8) + (lane << 2);
#pragma unroll
                for (int q = 0; q < 16; ++q) {
                    const float* p = hb + (q << 8);
                    hl[4*q+0] = ldg_coh(p+0);
                    hl[4*q+1] = ldg_coh(p+1);
                    hl[4*q+2] = ldg_coh(p+2);
                    hl[4*q+3] = ldg_coh(p+3);
                }
#pragma unroll
                for (int q = 0; q < 16; ++q) {
                    const int k = kh0 + 4*q;
#pragma unroll
                    for (int j = 0; j < 16; ++j) {
                        const int jg = ((j >> 2) << 9) + ub + (j & 3);
                        const float* wr = Whh0 + (size_t)jg * HH + k;
                        acc[j] = fmaf(hl[4*q+0], wr[0], acc[j]);
                        acc[j] = fmaf(hl[4*q+1], wr[1], acc[j]);
                        acc[j] = fmaf(hl[4*q+2], wr[2], acc[j]);
                        acc[j] = fmaf(hl[4*q+3], wr[3], acc[j]);
                    }
                }
            } else {
                // ---- layer1 @ t=s-1: input = h0[t], hidden = h1[t-1]
                const float* hb0 = h0T + (((s - 1) & 1) << 15)
                                 + ((kh0 >> 2) << 8) + (lane << 2);
#pragma unroll
                for (int q = 0; q < 16; ++q) {
                    const float* p = hb0 + (q << 8);
                    hl[4*q+0] = ldg_coh(p+0);
                    hl[4*q+1] = ldg_coh(p+1);
                    hl[4*q+2] = ldg_coh(p+2);
                    hl[4*q+3] = ldg_coh(p+3);
                }
#pragma unroll
                for (int q = 0; q < 16; ++q) {
                    const int k = kh0 + 4*q;
#pragma unroll
                    for (int j = 0; j < 16; ++j) {
                        const int jg = ((j >> 2) << 9) + ub + (j & 3);
                        const float* wr = Wih1 + (size_t)jg * HH + k;
                        acc[j] = fmaf(hl[4*q+0], wr[0], acc[j]);
                        acc[j] = fmaf(hl[4*q+1], wr[1], acc[j]);
                        acc[j] = fmaf(hl[4*q+2], wr[2], acc[j]);
                        acc[j] = fmaf(hl[4*q+3], wr[3], acc[j]);
                    }
                }
                const float* hb1 = h1T + ((s & 1) << 15)
                                 + ((kh0 >> 2) << 8) + (lane << 2);
#pragma unroll
                for (int q = 0; q < 16; ++q) {
                    const float* p = hb1 + (q << 8);
                    hl[4*q+0] = ldg_coh(p+0);
                    hl[4*q+1] = ldg_coh(p+1);
                    hl[4*q+2] = ldg_coh(p+2);
                    hl[4*q+3] = ldg_coh(p+3);
                }
#pragma unroll
                for (int q = 0; q < 16; ++q) {
                    const int k = kh0 + 4*q;
#pragma unroll
                    for (int j = 0; j < 16; ++j) {
                        const int jg = ((j >> 2) << 9) + ub + (j & 3);
                        const float* wr = Whh1 + (size_t)jg * HH + k;
                        acc[j] = fmaf(hl[4*q+0], wr[0], acc[j]);
                        acc[j] = fmaf(hl[4*q+1], wr[1], acc[j]);
                        acc[j] = fmaf(hl[4*q+2], wr[2], acc[j]);
                        acc[j] = fmaf(hl[4*q+3], wr[3], acc[j]);
                    }
                }
            }

            __syncthreads();
#pragma unroll
            for (int j = 0; j < 16; ++j) atomicAdd(&gsh[j][lane], acc[j]);
            __syncthreads();

            if (tid < 256) {               // 4 u x 64 b state updates
                const int b  = tid & 63;
                const int ul = tid >> 6;
                const int u  = ub + ul;
                const float iv = sigmoidf_(gsh[ul][b]);
                const float fv = sigmoidf_(gsh[4 + ul][b]);
                const float gv = tanhf(gsh[8 + ul][b]);
                const float ov = sigmoidf_(gsh[12 + ul][b]);
                float* cbuf = layer ? c1 : c0;          // block-private: cached
                const size_t ci = ((size_t)b << 9) + u;
                const float cn = fv * cbuf[ci] + iv * gv;
                cbuf[ci] = cn;
                const float hn = ov * tanhf(cn);
                float* hTn = layer ? (h1T + (((s - 1) & 1) << 15))
                                   : (h0T + ((s & 1) << 15));
                stg_coh(hTn + ((size_t)tile << 8) + (b << 2) + ul, hn);
                if (layer) out[(((size_t)b * TT) + t) * HH + u] = hn;  // write-only: cached
            }
        }

        // ---- grid barrier: relaxed AGENT atomics, no cache-flushing fences.
        // __syncthreads drains vmcnt(0): all h stores (coherent-point acked)
        // complete before tid 0 sends the arrive token.
        __syncthreads();
        if (tid == 0) {
            const int ph = __hip_atomic_load(phase, __ATOMIC_RELAXED, __HIP_MEMORY_SCOPE_AGENT);
            const int tk = __hip_atomic_fetch_add(cnt, 1, __ATOMIC_RELAXED, __HIP_MEMORY_SCOPE_AGENT);
            if (tk == NB - 1) {
                __hip_atomic_store(cnt, 0, __ATOMIC_RELAXED, __HIP_MEMORY_SCOPE_AGENT);
                __hip_atomic_fetch_add(phase, 1, __ATOMIC_RELAXED, __HIP_MEMORY_SCOPE_AGENT);
            } else {
                while (__hip_atomic_load(phase, __ATOMIC_RELAXED, __HIP_MEMORY_SCOPE_AGENT) == ph)
                    __builtin_amdgcn_s_sleep(1);
            }
        }
        __syncthreads();    // also a compiler barrier: h loads can't hoist above
    }
}

extern "C" void kernel_launch(void* const* d_in, const int* in_sizes, int n_in,
                              void* d_out, int out_size, void* d_ws, size_t ws_size,
                              hipStream_t stream) {
    (void)in_sizes; (void)n_in; (void)out_size; (void)ws_size;
    const float* x    = (const float*)d_in[0];
    const float* Wih0 = (const float*)d_in[1];
    const float* Whh0 = (const float*)d_in[2];
    const float* bi0  = (const float*)d_in[3];
    const float* bh0  = (const float*)d_in[4];
    const float* Wih1 = (const float*)d_in[5];
    const float* Whh1 = (const float*)d_in[6];
    const float* bi1  = (const float*)d_in[7];
    const float* bh1  = (const float*)d_in[8];
    float* out = (float*)d_out;
    float* ws  = (float*)d_ws;

    // ws layout (floats): h0T pp [2][32768] | c0 [32768] | h1T pp [2][32768] | c1 [32768] | barrier
    float* h0T = ws;
    float* c0  = ws + 65536;
    float* h1T = ws + 98304;
    float* c1  = ws + 163840;
    int*   bar = (int*)(ws + 196608);

    // zero state + barrier vars (ws is re-poisoned 0xAA before every timed call)
    hipMemsetAsync(d_ws, 0, 196608 * sizeof(float) + 256, stream);

    void* args[] = {
        (void*)&x, (void*)&Wih0, (void*)&Whh0, (void*)&bi0, (void*)&bh0,
        (void*)&Wih1, (void*)&Whh1, (void*)&bi1, (void*)&bh1,
        (void*)&h0T, (void*)&c0, (void*)&h1T, (void*)&c1,
        (void*)&out, (void*)&bar
    };
    hipLaunchCooperativeKernel((const void*)lstm_persist, dim3(NB), dim3(512),
                               args, 0, stream);
}